// Round 1
// baseline (345.531 us; speedup 1.0000x reference)
//
#include <hip/hip_runtime.h>
#include <stdint.h>

// SpatialGraphConv fused: 1x1 conv (192x64 GEMM) -> graph matmul (K=75) -> BN.
// B=64, C_in=64, T=300, V=25, K=3, C_out=64.  All MFMA bf16 16x16x32, fp32 acc.
//
// Main kernel: one block per (b, 4-t tile).  LDS operands stored in
// "fragment-linear" order (chunk addr = tile*1024 + lane*16) so every MFMA
// operand load is a conflict-free lane-linear ds_read_b128.

#define TT 4            // t per block
#define NPIX (TT * 25)  // 100 pixels per tile
#define NT1 7           // ceil(112/16) n-tiles for stage 1 (cols 100..111 pad)
#define NBLK 4800       // 64 b * 75 t-tiles

typedef short bf16x8 __attribute__((ext_vector_type(8)));
typedef float f32x4 __attribute__((ext_vector_type(4)));

__device__ inline short f2bf(float f) {
    union { float f; uint32_t u; } v; v.f = f;
    uint32_t u = v.u;
    u += 0x7fffu + ((u >> 16) & 1u);   // RNE
    return (short)(u >> 16);
}

__global__ __launch_bounds__(256, 2) void sgc_main(
    const float* __restrict__ x, const float* __restrict__ W,
    const float* __restrict__ bias, const float* __restrict__ A,
    float* __restrict__ out, float* __restrict__ stats_part)
{
    // fragment-linear LDS: element (row m/k-contig) chunks of 8 bf16 = 16 B
    __shared__ __align__(16) short xT[7168];     // 7 nt * 2 kb * 64 lanes * 8
    __shared__ __align__(16) short Ylds[24576];  // 4 t * 4 mt * 3 kb * 64 * 8
    __shared__ __align__(16) short Acat[3072];   // 2 nt * 3 kb * 64 * 8

    const int tid  = threadIdx.x;
    const int lane = tid & 63;
    const int wave = tid >> 6;
    const int bid  = blockIdx.x;
    const int b    = bid / 75;
    const int t0   = (bid % 75) * TT;

    // ---- zero Ylds (stage-2 K pads kv%32 in 25..31 must be 0) ----
    bf16x8 z8 = {0,0,0,0,0,0,0,0};
    #pragma unroll
    for (int j = 0; j < 12; ++j)
        *(bf16x8*)&Ylds[(tid + 256 * j) * 8] = z8;

    // ---- stage x -> xT (bf16, fragment-linear for stage-1 B operand) ----
    // element (ci=k, n): tile=(n>>4)*2+(ci>>5), lane=((ci>>3)&3)*16+(n&15), j=ci&7
    {
        const size_t xbase = (size_t)b * 480000 + (size_t)t0 * 25;
        #pragma unroll
        for (int j = 0; j < 7; ++j) {
            int e4 = tid + 256 * j;          // quad over 64ci x 25 quads
            if (e4 < 1600) {
                int ci = e4 / 25;
                int n  = (e4 % 25) * 4;
                const float4 v = *(const float4*)&x[xbase + (size_t)ci * 7500 + n];
                #pragma unroll
                for (int i = 0; i < 4; ++i) {
                    int nn = n + i;
                    int sidx = ((nn >> 4) * 2 + (ci >> 5)) * 512
                             + ((ci >> 3) & 3) * 128 + (nn & 15) * 8 + (ci & 7);
                    xT[sidx] = f2bf(((const float*)&v)[i]);
                }
            }
        }
    }

    // ---- stage Acat: Acat[kv][w] = A[k][v][w], kv=k*32+v, pads zero ----
    #pragma unroll
    for (int j = 0; j < 12; ++j) {
        int s    = tid + 256 * j;        // 0..3071
        int tile = s >> 9;               // nt2*3 + kb2
        int q    = s & 511;
        int oct  = q >> 7;
        int wl   = (q >> 3) & 15;
        int jj   = s & 7;
        int nt2  = tile / 3, kb2 = tile % 3;
        int w    = nt2 * 16 + wl;
        int kv   = kb2 * 32 + oct * 8 + jj;
        int k    = kv >> 5, v = kv & 31;
        float val = (v < 25 && w < 25) ? A[(k * 25 + v) * 25 + w] : 0.f;
        Acat[s] = f2bf(val);
    }

    // ---- W A-frags straight from global (L2-resident, 49 KB total) ----
    bf16x8 wfrag[3][2];
    #pragma unroll
    for (int mti = 0; mti < 3; ++mti) {
        int o = (wave * 3 + mti) * 16 + (lane & 15);
        #pragma unroll
        for (int kb = 0; kb < 2; ++kb) {
            int ci0 = kb * 32 + (lane >> 4) * 8;
            const float4 f0 = *(const float4*)&W[o * 64 + ci0];
            const float4 f1 = *(const float4*)&W[o * 64 + ci0 + 4];
            bf16x8 f;
            f[0] = f2bf(f0.x); f[1] = f2bf(f0.y); f[2] = f2bf(f0.z); f[3] = f2bf(f0.w);
            f[4] = f2bf(f1.x); f[5] = f2bf(f1.y); f[6] = f2bf(f1.z); f[7] = f2bf(f1.w);
            wfrag[mti][kb] = f;
        }
    }

    // bias per (mti, r):  o = (wave*3+mti)*16 + (lane>>4)*4 + r
    float bval[3][4];
    #pragma unroll
    for (int mti = 0; mti < 3; ++mti)
        #pragma unroll
        for (int r = 0; r < 4; ++r)
            bval[mti][r] = bias[(wave * 3 + mti) * 16 + (lane >> 4) * 4 + r];

    __syncthreads();

    // ---- stage 1: Y(192 x 100) = W(192x64) @ x(64x100), per-wave 3 m-tiles ----
    f32x4 acc[3][NT1];
    #pragma unroll
    for (int mti = 0; mti < 3; ++mti)
        #pragma unroll
        for (int nt = 0; nt < NT1; ++nt) {
            f32x4 zf = {0.f, 0.f, 0.f, 0.f};
            acc[mti][nt] = zf;
        }

    #pragma unroll
    for (int nt = 0; nt < NT1; ++nt) {
        bf16x8 xb0 = *(const bf16x8*)&xT[((nt * 2 + 0) * 64 + lane) * 8];
        bf16x8 xb1 = *(const bf16x8*)&xT[((nt * 2 + 1) * 64 + lane) * 8];
        #pragma unroll
        for (int mti = 0; mti < 3; ++mti) {
            acc[mti][nt] = __builtin_amdgcn_mfma_f32_16x16x32_bf16(
                wfrag[mti][0], xb0, acc[mti][nt], 0, 0, 0);
            acc[mti][nt] = __builtin_amdgcn_mfma_f32_16x16x32_bf16(
                wfrag[mti][1], xb1, acc[mti][nt], 0, 0, 0);
        }
    }

    // ---- epilogue: Y + bias -> Ylds (bf16, fragment-linear for stage-2 A) ----
    #pragma unroll
    for (int nt = 0; nt < NT1; ++nt) {
        int n = nt * 16 + (lane & 15);
        if (n < NPIX) {
            int t = n / 25, v = n % 25;
            #pragma unroll
            for (int mti = 0; mti < 3; ++mti) {
                int obase = (wave * 3 + mti) * 16 + (lane >> 4) * 4;
                #pragma unroll
                for (int r = 0; r < 4; ++r) {
                    int o = obase + r;
                    int k = o >> 6, c = o & 63;
                    int kv = k * 32 + v;
                    float val = acc[mti][nt][r] + bval[mti][r];
                    int sidx = ((t * 4 + (c >> 4)) * 3 + k) * 512
                             + ((kv >> 3) & 3) * 128 + (c & 15) * 8 + (kv & 7);
                    Ylds[sidx] = f2bf(val);
                }
            }
        }
    }
    __syncthreads();

    // ---- stage 2: out_t(64x25) = Yt(64x96) @ Acat(96x25), per t ----
    bf16x8 bfrag2[2][3];
    #pragma unroll
    for (int nt2 = 0; nt2 < 2; ++nt2)
        #pragma unroll
        for (int kb2 = 0; kb2 < 3; ++kb2)
            bfrag2[nt2][kb2] = *(const bf16x8*)&Acat[((nt2 * 3 + kb2) * 64 + lane) * 8];

    float ssum[4] = {0.f, 0.f, 0.f, 0.f};
    float ssq[4]  = {0.f, 0.f, 0.f, 0.f};
    const int c0 = wave * 16 + (lane >> 4) * 4;

    #pragma unroll
    for (int t = 0; t < TT; ++t) {
        bf16x8 a2[3];
        #pragma unroll
        for (int kb2 = 0; kb2 < 3; ++kb2)
            a2[kb2] = *(const bf16x8*)&Ylds[(((t * 4 + wave) * 3 + kb2) * 64 + lane) * 8];

        f32x4 acc2[2];
        #pragma unroll
        for (int nt2 = 0; nt2 < 2; ++nt2) {
            f32x4 zf = {0.f, 0.f, 0.f, 0.f};
            acc2[nt2] = zf;
            #pragma unroll
            for (int kb2 = 0; kb2 < 3; ++kb2)
                acc2[nt2] = __builtin_amdgcn_mfma_f32_16x16x32_bf16(
                    a2[kb2], bfrag2[nt2][kb2], acc2[nt2], 0, 0, 0);
        }

        #pragma unroll
        for (int nt2 = 0; nt2 < 2; ++nt2) {
            int w = nt2 * 16 + (lane & 15);
            bool valid = (w < 25);
            #pragma unroll
            for (int r = 0; r < 4; ++r) {
                float val = acc2[nt2][r];
                if (valid) {
                    out[(size_t)((b * 64 + c0 + r) * 300 + t0 + t) * 25 + w] = val;
                    ssum[r] += val;
                    ssq[r]  += val * val;
                }
            }
        }
    }

    // ---- per-channel partial stats: reduce over lane&15 (the w lanes) ----
    #pragma unroll
    for (int r = 0; r < 4; ++r) {
        float s = ssum[r], q = ssq[r];
        #pragma unroll
        for (int d = 1; d < 16; d <<= 1) {
            s += __shfl_xor(s, d);
            q += __shfl_xor(q, d);
        }
        if ((lane & 15) == 0) {
            int c = c0 + r;
            int slot = bid & 63;
            atomicAdd(&stats_part[slot * 128 + c], s);
            atomicAdd(&stats_part[slot * 128 + 64 + c], q);
        }
    }
}

__global__ void sgc_finalize(const float* __restrict__ stats_part,
                             const float* __restrict__ gamma,
                             const float* __restrict__ beta,
                             float* __restrict__ scaleshift)
{
    int c = threadIdx.x;  // 64 threads
    float s = 0.f, q = 0.f;
    #pragma unroll 8
    for (int slot = 0; slot < 64; ++slot) {
        s += stats_part[slot * 128 + c];
        q += stats_part[slot * 128 + 64 + c];
    }
    const float invN = 1.f / 480000.f;
    float mean = s * invN;
    float var  = q * invN - mean * mean;
    float rstd = rsqrtf(var + 1e-5f);
    float sc = rstd * gamma[c];
    scaleshift[c]      = sc;
    scaleshift[64 + c] = beta[c] - mean * sc;
}

__global__ __launch_bounds__(256) void sgc_norm(float* __restrict__ out,
                                                const float* __restrict__ scaleshift)
{
    const int total4 = 30720000 / 4;
    int stride = gridDim.x * 256;
    for (int i = blockIdx.x * 256 + threadIdx.x; i < total4; i += stride) {
        int c = (i / 1875) & 63;   // 7500 floats per (b,c) row; /4 = 1875 quads
        float sc = scaleshift[c], sh = scaleshift[64 + c];
        float4 v = *((float4*)out + i);
        v.x = v.x * sc + sh;
        v.y = v.y * sc + sh;
        v.z = v.z * sc + sh;
        v.w = v.w * sc + sh;
        *((float4*)out + i) = v;
    }
}

extern "C" void kernel_launch(void* const* d_in, const int* in_sizes, int n_in,
                              void* d_out, int out_size, void* d_ws, size_t ws_size,
                              hipStream_t stream)
{
    const float* x     = (const float*)d_in[0];
    const float* W     = (const float*)d_in[1];
    const float* bias  = (const float*)d_in[2];
    const float* A     = (const float*)d_in[3];
    const float* gamma = (const float*)d_in[4];
    const float* beta  = (const float*)d_in[5];
    float* out = (float*)d_out;

    float* stats      = (float*)d_ws;        // 64 slots * 128 floats = 32 KB
    float* scaleshift = stats + 64 * 128;    // 128 floats

    hipMemsetAsync(stats, 0, 64 * 128 * sizeof(float), stream);
    sgc_main<<<NBLK, 256, 0, stream>>>(x, W, bias, A, out, stats);
    sgc_finalize<<<1, 64, 0, stream>>>(stats, gamma, beta, scaleshift);
    sgc_norm<<<4096, 256, 0, stream>>>(out, scaleshift);
}